// Round 3
// baseline (330.846 us; speedup 1.0000x reference)
//
#include <hip/hip_runtime.h>
#include <hip/hip_bf16.h>

// VeRA: out = SCALE * d_B[o] * ((x @ (d_A*A)^T) @ B^T)
// GEMM1 (split-K=8, BN=256=full rank): part[z] = x @ Ab^T over K-chunk (K=512 each)
// reduce: t = bf16(sum_z part[z]);  GEMM2: out = SCALE*d_B * (t @ Bb^T)
//
// All LDS tiles use an XOR swizzle on the *global-fetch* side so that
// global_load_lds (lane-linear LDS dst) can coexist with conflict-free
// fragment reads: LDS 16B-unit u of row r holds global k-unit (p ^ f(r)).
// Readers hit all 8 four-bank groups 2x per 16 lanes -> free (m136).

#define SCALE_F 0.125f
#define M_TOT 8192
#define K_IN 4096
#define RANK 256
#define N_OUT 4096
#define S_SPLIT 8
#define KC 512    // K_IN / S_SPLIT

typedef __bf16 bf16_t;
typedef __bf16 bf16x8 __attribute__((ext_vector_type(8)));
typedef __bf16 bf16x4 __attribute__((ext_vector_type(4)));
typedef float f32x4 __attribute__((ext_vector_type(4)));

typedef __attribute__((address_space(3))) unsigned int lds_u32_t;
typedef const __attribute__((address_space(1))) unsigned int glob_u32_t;

__device__ __forceinline__ void async16(const void* g, void* l) {
    __builtin_amdgcn_global_load_lds((glob_u32_t*)g, (lds_u32_t*)l, 16, 0, 0);
}

// ---- fused convert: A (fold d_A) and B -> bf16 ----
__global__ __launch_bounds__(256) void conv_AB(const float* __restrict__ A,
                                               const float* __restrict__ dA,
                                               const float* __restrict__ B,
                                               bf16_t* __restrict__ Ab,
                                               bf16_t* __restrict__ Bb) {
    int b = blockIdx.x;
    int idx = (b & 1023) * 256 + threadIdx.x;
    if (b < 1024) {
        float4 v = ((const float4*)A)[idx];
        float s = dA[idx >> 10];
        bf16x4 o;
        o.x = (bf16_t)(v.x * s); o.y = (bf16_t)(v.y * s);
        o.z = (bf16_t)(v.z * s); o.w = (bf16_t)(v.w * s);
        ((bf16x4*)Ab)[idx] = o;
    } else {
        float4 v = ((const float4*)B)[idx];
        bf16x4 o;
        o.x = (bf16_t)v.x; o.y = (bf16_t)v.y; o.z = (bf16_t)v.z; o.w = (bf16_t)v.w;
        ((bf16x4*)Bb)[idx] = o;
    }
}

// ---- GEMM1: part[z][8192][256] = x(fp32) @ Ab^T over K-chunk z ----
// BM=64, BN=256 (full rank -> x fetched once), BK=32. grid (128, 8) = 1024 blocks.
// 4 waves 2x2, wave tile 32x128 (acc 2x8). LDS 24 KB -> 4+ blocks/CU.
__global__ __launch_bounds__(256) void gemm1(const float* __restrict__ x,
                                             const bf16_t* __restrict__ Ab,
                                             bf16_t* __restrict__ part) {
    __shared__ float  sX[64 * 32];    // 8 KB, 8 units/row, XOR-swizzled
    __shared__ bf16_t sA[256 * 32];   // 16 KB, 4 units/row, XOR-swizzled
    const int tid = threadIdx.x;
    const int lane = tid & 63, wave = tid >> 6;
    const int wm = wave >> 1, wn = wave & 1;
    const int l15 = lane & 15, quad = lane >> 4;
    const int bm = blockIdx.x * 64;
    const int k0 = blockIdx.y * KC;

    f32x4 acc[2][8];
    const f32x4 zero = {0.f, 0.f, 0.f, 0.f};
    #pragma unroll
    for (int i = 0; i < 2; i++)
        #pragma unroll
        for (int j = 0; j < 8; j++) acc[i][j] = zero;

    for (int kt = 0; kt < KC; kt += 32) {
        // sX: 64 rows x 8 fp32-units; unit u=(m,p) holds k-unit p^(m&7)
        #pragma unroll
        for (int c = 0; c < 2; c++) {
            int u = c * 256 + tid;
            int m = u >> 3, p = u & 7;
            int kcu = p ^ (m & 7);
            async16(&x[(size_t)(bm + m) * K_IN + k0 + kt + kcu * 4], &sX[u * 4]);
        }
        // sA: 256 rows x 4 bf16-units; unit u=(n,p) holds k-unit p^((n>>1)&3)
        #pragma unroll
        for (int c = 0; c < 4; c++) {
            int u = c * 256 + tid;
            int n = u >> 2, p = u & 3;
            int kc8 = p ^ ((n >> 1) & 3);
            async16(&Ab[(size_t)n * K_IN + k0 + kt + kc8 * 8], &sA[u * 8]);
        }
        __syncthreads();
        bf16x8 af[2], bfr[8];
        #pragma unroll
        for (int i = 0; i < 2; i++) {
            int m = wm * 32 + i * 16 + l15;
            int p0 = (quad * 2) ^ (m & 7);       // k-units 2q,2q+1 -> p0, p0^1
            f32x4 v0 = *(const f32x4*)&sX[m * 32 + p0 * 4];
            f32x4 v1 = *(const f32x4*)&sX[m * 32 + (p0 ^ 1) * 4];
            bf16x8 t;
            t[0] = (bf16_t)v0[0]; t[1] = (bf16_t)v0[1];
            t[2] = (bf16_t)v0[2]; t[3] = (bf16_t)v0[3];
            t[4] = (bf16_t)v1[0]; t[5] = (bf16_t)v1[1];
            t[6] = (bf16_t)v1[2]; t[7] = (bf16_t)v1[3];
            af[i] = t;
        }
        #pragma unroll
        for (int j = 0; j < 8; j++) {
            int n = wn * 128 + j * 16 + l15;
            int p = quad ^ ((n >> 1) & 3);
            bfr[j] = *(const bf16x8*)&sA[n * 32 + p * 8];
        }
        #pragma unroll
        for (int i = 0; i < 2; i++)
            #pragma unroll
            for (int j = 0; j < 8; j++)
                acc[i][j] = __builtin_amdgcn_mfma_f32_16x16x32_bf16(af[i], bfr[j], acc[i][j], 0, 0, 0);
        __syncthreads();
    }
    bf16_t* pp = part + (size_t)blockIdx.y * M_TOT * RANK;
    #pragma unroll
    for (int i = 0; i < 2; i++) {
        #pragma unroll
        for (int j = 0; j < 8; j++) {
            int col = wn * 128 + j * 16 + l15;
            #pragma unroll
            for (int r = 0; r < 4; r++) {
                int row = bm + wm * 32 + i * 16 + quad * 4 + r;
                pp[(size_t)row * RANK + col] = (bf16_t)acc[i][j][r];
            }
        }
    }
}

// ---- reduce: t = bf16(sum_z part[z]) ----
__global__ __launch_bounds__(256) void reduce_t(const bf16_t* __restrict__ part,
                                                bf16_t* __restrict__ t) {
    int i = (blockIdx.x * 256 + threadIdx.x) * 8;
    float s[8] = {0.f, 0.f, 0.f, 0.f, 0.f, 0.f, 0.f, 0.f};
    #pragma unroll
    for (int z = 0; z < S_SPLIT; z++) {
        bf16x8 v = *(const bf16x8*)&part[(size_t)z * M_TOT * RANK + i];
        #pragma unroll
        for (int e = 0; e < 8; e++) s[e] += (float)v[e];
    }
    bf16x8 o;
    #pragma unroll
    for (int e = 0; e < 8; e++) o[e] = (bf16_t)s[e];
    *(bf16x8*)&t[i] = o;
}

// ---- GEMM2: out[8192][4096] = SCALE*dB * (t @ Bb^T) ----
// BM=64, BN=64, BK=64 (4 iters). grid (128,64)=8192 blocks, 16 KB LDS -> 8 blocks/CU.
__global__ __launch_bounds__(256) void gemm2(const bf16_t* __restrict__ t,
                                             const bf16_t* __restrict__ Bb,
                                             const float* __restrict__ dB,
                                             float* __restrict__ out) {
    __shared__ bf16_t sT[64 * 64];   // 8 KB, 8 units/row, XOR-swizzled
    __shared__ bf16_t sB[64 * 64];   // 8 KB
    const int tid = threadIdx.x;
    const int lane = tid & 63, wave = tid >> 6;
    const int wm = wave >> 1, wn = wave & 1;
    const int l15 = lane & 15, quad = lane >> 4;
    const int bm = blockIdx.x * 64;
    const int bn = blockIdx.y * 64;

    f32x4 acc[2][2];
    const f32x4 zero = {0.f, 0.f, 0.f, 0.f};
    #pragma unroll
    for (int i = 0; i < 2; i++)
        #pragma unroll
        for (int j = 0; j < 2; j++) acc[i][j] = zero;

    for (int kt = 0; kt < RANK; kt += 64) {
        #pragma unroll
        for (int c = 0; c < 2; c++) {
            int u = c * 256 + tid;
            int row = u >> 3, p = u & 7;
            int kcu = p ^ (row & 7);
            async16(&t[(size_t)(bm + row) * RANK + kt + kcu * 8], &sT[u * 8]);
        }
        #pragma unroll
        for (int c = 0; c < 2; c++) {
            int u = c * 256 + tid;
            int row = u >> 3, p = u & 7;
            int kcu = p ^ (row & 7);
            async16(&Bb[(size_t)(bn + row) * RANK + kt + kcu * 8], &sB[u * 8]);
        }
        __syncthreads();
        #pragma unroll
        for (int ks = 0; ks < 2; ks++) {
            bf16x8 af[2], bfr[2];
            #pragma unroll
            for (int i = 0; i < 2; i++) {
                int row = wm * 32 + i * 16 + l15;
                int p = (ks * 4 + quad) ^ (row & 7);
                af[i] = *(const bf16x8*)&sT[row * 64 + p * 8];
            }
            #pragma unroll
            for (int j = 0; j < 2; j++) {
                int row = wn * 32 + j * 16 + l15;
                int p = (ks * 4 + quad) ^ (row & 7);
                bfr[j] = *(const bf16x8*)&sB[row * 64 + p * 8];
            }
            #pragma unroll
            for (int i = 0; i < 2; i++)
                #pragma unroll
                for (int j = 0; j < 2; j++)
                    acc[i][j] = __builtin_amdgcn_mfma_f32_16x16x32_bf16(af[i], bfr[j], acc[i][j], 0, 0, 0);
        }
        __syncthreads();
    }
    #pragma unroll
    for (int j = 0; j < 2; j++) {
        int col = bn + wn * 32 + j * 16 + l15;
        float db = dB[col] * SCALE_F;
        #pragma unroll
        for (int i = 0; i < 2; i++) {
            #pragma unroll
            for (int r = 0; r < 4; r++) {
                int row = bm + wm * 32 + i * 16 + quad * 4 + r;
                out[(size_t)row * N_OUT + col] = db * acc[i][j][r];
            }
        }
    }
}

extern "C" void kernel_launch(void* const* d_in, const int* in_sizes, int n_in,
                              void* d_out, int out_size, void* d_ws, size_t ws_size,
                              hipStream_t stream) {
    const float* x  = (const float*)d_in[0];
    const float* A  = (const float*)d_in[1];
    const float* B  = (const float*)d_in[2];
    const float* dA = (const float*)d_in[3];
    const float* dB = (const float*)d_in[4];
    float* out = (float*)d_out;

    char* ws = (char*)d_ws;
    bf16_t* Ab   = (bf16_t*)ws;                       // 2 MB
    bf16_t* Bb   = (bf16_t*)(ws + (1u << 21));        // 2 MB
    bf16_t* tt   = (bf16_t*)(ws + (1u << 22));        // 4 MB
    bf16_t* part = (bf16_t*)(ws + (1u << 23));        // 8 * 4 MB = 32 MB

    conv_AB<<<2048, 256, 0, stream>>>(A, dA, B, Ab, Bb);
    gemm1<<<dim3(128, S_SPLIT), 256, 0, stream>>>(x, Ab, part);
    reduce_t<<<1024, 256, 0, stream>>>(part, tt);
    gemm2<<<dim3(128, 64), 256, 0, stream>>>(tt, Bb, dB, out);
}